// Round 10
// baseline (1603.693 us; speedup 1.0000x reference)
//
#include <hip/hip_runtime.h>

// ---------- types ----------
typedef __bf16 bft;
typedef bft bf16x8 __attribute__((ext_vector_type(8)));
typedef bft bf16x4 __attribute__((ext_vector_type(4)));
typedef bft bf16x2 __attribute__((ext_vector_type(2)));
typedef float f32x4 __attribute__((ext_vector_type(4)));
typedef unsigned long long u64;
typedef unsigned int u32;
typedef u32 u32x4 __attribute__((ext_vector_type(4)));

#define LN_EPS 1e-5f

// B=32, S=256, H=1024, HL=512, E=256, L=5. All big GEMMs have K=1024.

__device__ __forceinline__ float sigmoidf_(float x) {
    return 1.f / (1.f + __expf(-x));
}
__device__ __forceinline__ float tanhf_(float x) {
    float e = __expf(-2.f * fabsf(x));
    float t = (1.f - e) / (1.f + e);
    return copysignf(t, x);
}

// ---------- f32 -> bf16 convert (vector-4) ----------
__global__ void cvt_f32_bf16(const float* __restrict__ in, bft* __restrict__ out, int n4) {
    int i = blockIdx.x * blockDim.x + threadIdx.x;
    if (i < n4) {
        float4 v = ((const float4*)in)[i];
        bf16x4 o = { (bft)v.x, (bft)v.y, (bft)v.z, (bft)v.w };
        ((bf16x4*)out)[i] = o;
    }
}

__global__ void zero_u32(u32* __restrict__ p, int n) {
    int i = blockIdx.x * blockDim.x + threadIdx.x;
    if (i < n) p[i] = 0u;
}

// ---------- transpose+convert W1/W2 ([L][K=h][N=d] f32 -> [L][N][K] bf16) ----------
__global__ __launch_bounds__(256) void transpose_cvt_w(
    const float* __restrict__ W1, const float* __restrict__ W2,
    bft* __restrict__ W1t, bft* __restrict__ W2t)
{
    __shared__ float tile[32][33];
    int z = blockIdx.z;
    int l = z >> 1;
    const float* src = ((z & 1) ? W2 : W1) + ((size_t)l << 20);
    bft* dst = ((z & 1) ? W2t : W1t) + ((size_t)l << 20);
    int tx = threadIdx.x & 31, ty = threadIdx.x >> 5;
    int bx = blockIdx.x * 32, by = blockIdx.y * 32;
    for (int r = ty; r < 32; r += 8)
        tile[r][tx] = src[(size_t)(by + r) * 1024 + bx + tx];
    __syncthreads();
    for (int r = ty; r < 32; r += 8)
        dst[(size_t)(bx + r) * 1024 + by + tx] = (bft)tile[tx][r];
}

// ---------- bf16 MFMA GEMM, 128x128 tile, BK=32, 4 waves, B^T ([N][K]) input ----------
__global__ __launch_bounds__(256) void gemm_bt(
    const bft* __restrict__ A, const bft* __restrict__ Bt,
    const float* __restrict__ bias, const int* __restrict__ langs,
    int langStrideB, int langStrideBias,
    float* __restrict__ outF, bft* __restrict__ outB,
    int remapLog, int remapMul, int ldc)
{
    const int K = 1024;
    int tn = blockIdx.x, tm = blockIdx.y;
    int row0 = tm * 128, col0 = tn * 128;
    int lang = langs ? langs[row0 >> 8] : 0;   // 256 rows per batch elem; 128-tile never crosses b
    const bft* Ap = A + (size_t)row0 * K;
    const bft* Bp = Bt + (size_t)lang * langStrideB + (size_t)col0 * K;
    const float* biasp = bias + (size_t)lang * langStrideBias + col0;

    __shared__ bft As[128 * 32];
    __shared__ bft Bs[128 * 32];

    int t = threadIdx.x;
    int lane = t & 63, wave = t >> 6;
    int wm = wave & 1, wn = wave >> 1;
    int lrow = lane & 15, quad = lane >> 4;

    f32x4 acc[4][4] = {};

    for (int k0 = 0; k0 < K; k0 += 32) {
        __syncthreads();
        for (int c = t; c < 512; c += 256) {       // 512 chunks of 8 bf16 (16B)
            int r = c >> 2, co = (c & 3) << 3;
            *(uint4*)(As + r * 32 + co) = *(const uint4*)(Ap + (size_t)r * K + k0 + co);
            *(uint4*)(Bs + r * 32 + co) = *(const uint4*)(Bp + (size_t)r * K + k0 + co);
        }
        __syncthreads();
        bf16x8 af[4], bfr[4];
#pragma unroll
        for (int i = 0; i < 4; ++i)
            af[i] = *(const bf16x8*)(As + (wm * 64 + i * 16 + lrow) * 32 + quad * 8);
#pragma unroll
        for (int j = 0; j < 4; ++j)
            bfr[j] = *(const bf16x8*)(Bs + (wn * 64 + j * 16 + lrow) * 32 + quad * 8);
#pragma unroll
        for (int i = 0; i < 4; ++i)
#pragma unroll
            for (int j = 0; j < 4; ++j)
                acc[i][j] = __builtin_amdgcn_mfma_f32_16x16x32_bf16(af[i], bfr[j], acc[i][j], 0, 0, 0);
    }

#pragma unroll
    for (int i = 0; i < 4; ++i) {
#pragma unroll
        for (int j = 0; j < 4; ++j) {
#pragma unroll
            for (int r = 0; r < 4; ++r) {
                int m = wm * 64 + i * 16 + quad * 4 + r;   // C row = quad*4+reg
                int n = wn * 64 + j * 16 + lrow;           // C col = lane&15
                int grow = row0 + m;
                int orow = remapLog ? ((grow & ((1 << remapLog) - 1)) * remapMul + (grow >> remapLog))
                                    : grow;
                float v = acc[i][j][r] + biasp[n];
                size_t idx = (size_t)orow * ldc + col0 + n;
                if (outF) outF[idx] = v;
                else outB[idx] = (bft)v;
            }
        }
    }
}

// ---------- LayerNorm + ReLU per row, f32 in -> bf16 out ----------
__global__ __launch_bounds__(256) void ln_relu_kernel(
    const float* __restrict__ h1, bft* __restrict__ a2,
    const float* __restrict__ ln_g, const float* __restrict__ ln_b,
    const int* __restrict__ langs)
{
    int row = blockIdx.x;
    int lang = langs[row >> 8];
    const float* x = h1 + (size_t)row * 1024;
    int t = threadIdx.x;
    float4 v = ((const float4*)x)[t];
    float s = v.x + v.y + v.z + v.w;
    float ss = v.x * v.x + v.y * v.y + v.z * v.z + v.w * v.w;
#pragma unroll
    for (int off = 32; off > 0; off >>= 1) {
        s += __shfl_down(s, off, 64);
        ss += __shfl_down(ss, off, 64);
    }
    __shared__ float red[8];
    int wave = t >> 6, lane = t & 63;
    if (lane == 0) { red[wave] = s; red[4 + wave] = ss; }
    __syncthreads();
    float S = red[0] + red[1] + red[2] + red[3];
    float SS = red[4] + red[5] + red[6] + red[7];
    float mean = S * (1.f / 1024.f);
    float var = SS * (1.f / 1024.f) - mean * mean;   // population var (ddof=0)
    float inv = rsqrtf(var + LN_EPS);
    float4 g = ((const float4*)(ln_g + (size_t)lang * 1024))[t];
    float4 b = ((const float4*)(ln_b + (size_t)lang * 1024))[t];
    float y0 = fmaxf(0.f, (v.x - mean) * inv * g.x + b.x);
    float y1 = fmaxf(0.f, (v.y - mean) * inv * g.y + b.y);
    float y2 = fmaxf(0.f, (v.z - mean) * inv * g.z + b.z);
    float y3 = fmaxf(0.f, (v.w - mean) * inv * g.w + b.w);
    bf16x4 o = { (bft)y0, (bft)y1, (bft)y2, (bft)y3 };
    ((bf16x4*)(a2 + (size_t)row * 1024))[t] = o;
}

// ---------- BiLSTM recurrence: 32 WGs, weight-stationary registers, MALL flags ----------
// 16 WGs/dir, each owns 32 h-cols. Whh slice (32 cols x 4 gates x 512 k = 128 KB)
// lives in VGPRs as persistent MFMA B-fragments (32 x bf16x8 per wave). LDS = 32 KB
// h staging only. N-fragment packs (i,f) / (g,o) gate pairs so the activation
// combines gates fully in-register via shfl_xor(8) — no gates LDS, 3 barriers/step.
// Transport = round-5 proven: sc0 sc1 stores -> vmcnt(0) ack -> barrier -> flag
// store; consumers poll the 16 producer flags (wave 0) then stage 32 KB coalesced.
// hg: [dir(2)][parity(2)][32][512] bf16. flags: [dir][256][32-slot stride] u32
// (prezeroed; only slots 0..15 used). gin: [s*32+b][4096] bf16 (dir-interleaved:
// cols dir*2048 + gate*512 + col).
__global__ __launch_bounds__(256, 1) void bilstm_kernel(
    const bft* __restrict__ gin, const bft* __restrict__ Whh_f, const bft* __restrict__ Whh_b,
    const int* __restrict__ mask, bft* __restrict__ ys, bft* __restrict__ hg,
    u32* __restrict__ flags)
{
    __shared__ u64 smem[4096];                 // 32 KB: h_prev staging (XOR-swizzled)
    bft* hs = (bft*)smem;
    u32* hsd = (u32*)smem;

    int blk = blockIdx.x;
    int dir = blk >> 4;
    int rank = blk & 15;
    int c0 = rank << 5;                 // this WG owns h cols [c0, c0+32)
    const bft* Whh = dir ? Whh_b : Whh_f;

    int t = threadIdx.x;
    int lane = t & 63, wave = t >> 6;
    int lrow = lane & 15, quad = lane >> 4;
    int j = lane & 7;
    int ghalf = (lane >> 3) & 1;        // 0: lane holds i/g gate cols; 1: f/o
    int hcol = c0 + wave * 8 + j;
    int bb = ghalf * 16 + quad * 4;     // batch base for this lane's 4 cells

    // ---- weight-stationary B fragments (persist across all 256 steps) ----
    // N-tile0 rows: n<8 -> i-gate col (c0+w*8+n), n>=8 -> f-gate col (n-8)
    // N-tile1 rows: n<8 -> g-gate, n>=8 -> o-gate
    bf16x8 bfr[2][16];
    {
        int colw = c0 + wave * 8 + (lrow & 7);
        int g0 = lrow >> 3;
        size_t row0 = (size_t)(g0 * 512 + colw) * 512;
        size_t row1 = (size_t)((2 + g0) * 512 + colw) * 512;
#pragma unroll
        for (int kt = 0; kt < 16; ++kt) {
            bfr[0][kt] = *(const bf16x8*)(Whh + row0 + kt * 32 + quad * 8);
            bfr[1][kt] = *(const bf16x8*)(Whh + row1 + kt * 32 + quad * 8);
        }
    }

    float cs[4] = {0.f, 0.f, 0.f, 0.f}, hp[4] = {0.f, 0.f, 0.f, 0.f};

    for (int it = 0; it < 256; ++it) {
        int tt = dir ? (255 - it) : it;

        // ---- gin + mask prefetch (independent of h; overlaps the poll) ----
        float gi[4], gf[4], gg[4], go[4];
        int mkv[4];
#pragma unroll
        for (int r = 0; r < 4; ++r) {
            int b = bb + r;
            const bft* gp = gin + ((size_t)(tt * 32 + b)) * 4096 + dir * 2048 + hcol;
            gi[r] = (float)gp[0];
            gf[r] = (float)gp[512];
            gg[r] = (float)gp[1024];
            go[r] = (float)gp[1536];
            mkv[r] = mask[b * 256 + tt];
        }

        // ---- wave 0 polls the 16 producer flags for this step ----
        if (it > 0) {
            if (wave == 0) {
                const u32* fp = flags + (size_t)(dir * 256 + it) * 32 + (lane & 15);
                int guard = 0;
                for (;;) {
                    u32 f;
                    asm volatile("global_load_dword %0, %1, off sc0 sc1\n\ts_waitcnt vmcnt(0)"
                                 : "=v"(f) : "v"(fp) : "memory");
                    if (__all(f != 0)) break;
                    __builtin_amdgcn_s_sleep(1);
                    if (++guard > (1 << 17)) break;   // hang insurance only
                }
            }
            __syncthreads();                                       // S1
        }

        // ---- stage h_prev (32 KB) into LDS (swizzled) ----
        if (it == 0) {
#pragma unroll
            for (int i = 0; i < 16; ++i)
                smem[t + i * 256] = 0ull;
        } else {
            const u32* hq = (const u32*)(hg + (size_t)(dir * 2 + (it & 1)) * 16384);
            u32x4 r8[8];
#pragma unroll
            for (int i = 0; i < 8; ++i)
                asm volatile("global_load_dwordx4 %0, %1, off sc0 sc1"
                             : "=v"(r8[i]) : "v"(hq + i * 1024 + t * 4) : "memory");
            asm volatile("s_waitcnt vmcnt(0)" ::: "memory");
            int mlo = t >> 6, b16S = t & 63;
#pragma unroll
            for (int i = 0; i < 8; ++i) {
                int m = i * 4 + mlo;
                *(u32x4*)(hsd + m * 256 + ((b16S ^ (m & 7)) << 2)) = r8[i];
            }
        }
        __syncthreads();                                           // S2

        // ---- gates = h_prev[32x512] @ Whh_slice^T[512x128], weights in VGPRs ----
        f32x4 acc[2][2] = {};
#pragma unroll
        for (int kt = 0; kt < 16; ++kt) {
            int b16 = kt * 4 + quad;
            bf16x8 a0 = *(const bf16x8*)(hs + lrow * 512 + ((b16 ^ (lrow & 7)) << 3));
            int ar1 = 16 + lrow;
            bf16x8 a1 = *(const bf16x8*)(hs + ar1 * 512 + ((b16 ^ (ar1 & 7)) << 3));
            acc[0][0] = __builtin_amdgcn_mfma_f32_16x16x32_bf16(a0, bfr[0][kt], acc[0][0], 0, 0, 0);
            acc[0][1] = __builtin_amdgcn_mfma_f32_16x16x32_bf16(a0, bfr[1][kt], acc[0][1], 0, 0, 0);
            acc[1][0] = __builtin_amdgcn_mfma_f32_16x16x32_bf16(a1, bfr[0][kt], acc[1][0], 0, 0, 0);
            acc[1][1] = __builtin_amdgcn_mfma_f32_16x16x32_bf16(a1, bfr[1][kt], acc[1][1], 0, 0, 0);
        }

        // ---- activation: 4 cells/lane, gates combined via shfl_xor(8), no LDS ----
        u32 yk[4];
        bft* hgN = hg + (size_t)(dir * 2 + ((it + 1) & 1)) * 16384;
#pragma unroll
        for (int r = 0; r < 4; ++r) {
            float t00 = __shfl_xor(acc[0][0][r], 8, 64);
            float t01 = __shfl_xor(acc[0][1][r], 8, 64);
            float t10 = __shfl_xor(acc[1][0][r], 8, 64);
            float t11 = __shfl_xor(acc[1][1][r], 8, 64);
            float vi, vf, vg, vo;
            if (ghalf == 0) { vi = acc[0][0][r]; vf = t00; vg = acc[0][1][r]; vo = t01; }
            else            { vi = t10; vf = acc[1][0][r]; vg = t11; vo = acc[1][1][r]; }
            float xi = vi + gi[r], xf = vf + gf[r], xg = vg + gg[r], xo = vo + go[r];
            float cn = sigmoidf_(xf) * cs[r] + sigmoidf_(xi) * tanhf_(xg);
            float hn = sigmoidf_(xo) * tanhf_(cn);
            float hout;
            if (mkv[r]) { cs[r] = cn; hp[r] = hn; hout = hn; }
            else        { hout = hp[r]; }
            union { bft b; unsigned short u; } cv; cv.b = (bft)hout;
            u32 hv = cv.u;
            yk[r] = mkv[r] ? (u32)cv.u : 0u;
            bft* ha = hgN + (size_t)(bb + r) * 512 + hcol;
            asm volatile("global_store_short %0, %1, off sc0 sc1" :: "v"(ha), "v"(hv) : "memory");
        }
        asm volatile("s_waitcnt vmcnt(0)" ::: "memory");           // own stores acked at MALL
        __syncthreads();                                           // S5
        if (t == 0 && it < 255) {
            u32* fa = flags + (size_t)(dir * 256 + it + 1) * 32 + rank;
            u32 one = 1u;
            asm volatile("global_store_dword %0, %1, off sc0 sc1" :: "v"(fa), "v"(one) : "memory");
        }
        // ys stores AFTER the signal — off the critical path
#pragma unroll
        for (int r = 0; r < 4; ++r) {
            union { bft b; unsigned short u; } cv; cv.u = (unsigned short)yk[r];
            ys[((size_t)(tt * 32 + bb + r)) * 1024 + dir * 512 + hcol] = cv.b;
        }
    }
}

// ---------- host launcher ----------
extern "C" void kernel_launch(void* const* d_in, const int* in_sizes, int n_in,
                              void* d_out, int out_size, void* d_ws, size_t ws_size,
                              hipStream_t stream)
{
    const float* X     = (const float*)d_in[0];   // [32,256,1024]
    const int*   amask = (const int*)d_in[1];     // [32,256]
    const int*   langs = (const int*)d_in[2];     // [32]
    const float* W1    = (const float*)d_in[3];   // [5,1024,1024] (K-major)
    const float* b1    = (const float*)d_in[4];   // [5,1024]
    const float* ln_g  = (const float*)d_in[5];
    const float* ln_b  = (const float*)d_in[6];
    const float* W2    = (const float*)d_in[7];
    const float* b2    = (const float*)d_in[8];
    const float* Wih_f = (const float*)d_in[9];   // [2048,1024] = [N][K]
    const float* Whh_f = (const float*)d_in[10];  // [2048,512]
    const float* b_f   = (const float*)d_in[11];  // [2048]
    const float* Wih_b = (const float*)d_in[12];
    const float* Whh_b = (const float*)d_in[13];
    const float* b_b   = (const float*)d_in[14];
    const float* Wp    = (const float*)d_in[15];  // [256,1024] = [N][K]
    const float* bp    = (const float*)d_in[16];
    float* out = (float*)d_out;

    char* ws = (char*)d_ws;
    size_t off = 0;
    auto alloc = [&](size_t bytes) -> void* {
        void* p = ws + off;
        off += (bytes + 255) & ~(size_t)255;
        return p;
    };
    bft* Xbf   = (bft*)alloc(8192ull * 1024 * 2);
    bft* W1t   = (bft*)alloc(5ull * 1024 * 1024 * 2);
    bft* W2t   = (bft*)alloc(5ull * 1024 * 1024 * 2);
    bft* Wihf  = (bft*)alloc(2048ull * 1024 * 2);   // must stay contiguous with Wihb
    bft* Wihb  = (bft*)alloc(2048ull * 1024 * 2);
    bft* Whhf  = (bft*)alloc(2048ull * 512 * 2);
    bft* Whhb  = (bft*)alloc(2048ull * 512 * 2);
    bft* Wpb   = (bft*)alloc(256ull * 1024 * 2);
    float* h1  = (float*)alloc(8192ull * 1024 * 4);
    bft* a2    = (bft*)alloc(8192ull * 1024 * 2);
    bft* adapt = (bft*)alloc(8192ull * 1024 * 2);
    bft* gin   = (bft*)alloc(8192ull * 4096 * 2);   // [s*32+b][4096], dirs interleaved
    bft* ysb   = (bft*)alloc(256ull * 32 * 1024 * 2);
    bft* hg    = (bft*)alloc(2ull * 2 * 32 * 512 * 2);   // 128 KB
    u32* flags = (u32*)alloc(2ull * 256 * 32 * 4);       // 64 KB
    float* bcat = (float*)alloc(4096 * 4);
    (void)ws_size; (void)in_sizes; (void)n_in; (void)out_size;

    auto cvt = [&](const float* src, bft* dst, int n) {
        int n4 = n >> 2;
        hipLaunchKernelGGL(cvt_f32_bf16, dim3((n4 + 255) / 256), dim3(256), 0, stream, src, dst, n4);
    };
    cvt(X, Xbf, 8192 * 1024);
    cvt(Wih_f, Wihf, 2048 * 1024);
    cvt(Wih_b, Wihb, 2048 * 1024);
    cvt(Whh_f, Whhf, 2048 * 512);
    cvt(Whh_b, Whhb, 2048 * 512);
    cvt(Wp, Wpb, 256 * 1024);
    hipLaunchKernelGGL(zero_u32, dim3(64), dim3(256), 0, stream, flags, 2 * 256 * 32);
    hipMemcpyAsync(bcat, b_f, 2048 * 4, hipMemcpyDeviceToDevice, stream);
    hipMemcpyAsync(bcat + 2048, b_b, 2048 * 4, hipMemcpyDeviceToDevice, stream);
    hipLaunchKernelGGL(transpose_cvt_w, dim3(32, 32, 10), dim3(256), 0, stream, W1, W2, W1t, W2t);

    // Adapter GEMM1: h1 = X @ W1[lang] + b1[lang]   (f32 out for LN)
    hipLaunchKernelGGL(gemm_bt, dim3(8, 64), dim3(256), 0, stream,
        Xbf, W1t, b1, langs, 1024 * 1024, 1024, h1, (bft*)nullptr, 0, 0, 1024);
    // LN + ReLU -> a2 (bf16)
    hipLaunchKernelGGL(ln_relu_kernel, dim3(8192), dim3(256), 0, stream, h1, a2, ln_g, ln_b, langs);
    // Adapter GEMM2: adapt = a2 @ W2[lang] + b2[lang]   (bf16 out)
    hipLaunchKernelGGL(gemm_bt, dim3(8, 64), dim3(256), 0, stream,
        a2, W2t, b2, langs, 1024 * 1024, 1024, (float*)nullptr, adapt, 0, 0, 1024);
    // Input gates (both dirs fused, N=4096): gin = adapt @ [Wih_f;Wih_b]^T + bcat,
    // row remap (b*256+s) -> (s*32+b), ldc 4096
    hipLaunchKernelGGL(gemm_bt, dim3(32, 64), dim3(256), 0, stream,
        adapt, Wihf, bcat, (const int*)nullptr, 0, 0, (float*)nullptr, gin, 8, 32, 4096);
    // Recurrence (cooperative, 32 WGs)
    {
        void* args[] = { (void*)&gin, (void*)&Whhf, (void*)&Whhb,
                         (void*)&amask, (void*)&ysb, (void*)&hg, (void*)&flags };
        hipLaunchCooperativeKernel((const void*)bilstm_kernel, dim3(32), dim3(256), args, 0, stream);
    }
    // Projection: out = ys @ Wp^T + bp, remap row (s*32+b) -> (b*256+s), ldc 256
    hipLaunchKernelGGL(gemm_bt, dim3(2, 64), dim3(256), 0, stream,
        ysb, Wpb, bp, (const int*)nullptr, 0, 0, out, (bft*)nullptr, 5, 256, 256);
}